// Round 2
// baseline (443.389 us; speedup 1.0000x reference)
//
#include <hip/hip_runtime.h>
#include <math.h>

// CGBlock fused kernel for MI355X (gfx950) — round 3 (re-run; previous
// round died to a container-acquire infra failure, not a kernel fault).
//
// Shapes: B=16, C=256, H=W=128, G=8, Cg=32, K=4.
// out = x + rt*(top_w2 @ yt) + rs*(soft_w2 @ y)     [rt+rs=1 folds the mix]
//
// R3 changes vs R2 (theory: occupancy-limited phase serialization):
//  - Epilogue restructured gg-outer, accumulating directly INTO va/vb.
//    This removes the yf[8]/tf[8] f32x2 register block (32 VGPRs) that was
//    live across the whole 1024-FMA epilogue. Per gg: 2 ds_read_b64 + 128
//    FMAs with SGPR coefficients.
//  - __launch_bounds__(512, 4): cap VGPRs at 128 so two 8-wave blocks fit
//    per CU (16 waves). With one block/CU the mid-kernel barrier serialized
//    load-phase / VALU-phase / store-phase; two blocks let one block's
//    streaming overlap the other's softmax+top4+FMA phase.
//
// Mapping (unchanged): block = 512 threads = 8 waves; wave w = group w;
// lane = 2 consecutive spatial positions (f32x2, 512 B per wave-instr,
// nontemporal both ways, zero over-fetch). g is wave-uniform via
// readfirstlane so every weight index is an SGPR -> s_load + v_fmac with
// SGPR operand (no VMEM traffic in the epilogue).

#define G_ 8
#define K_ 4
#define CG_ 32
#define C_ 256
#define HW_ (128 * 128)

typedef __attribute__((ext_vector_type(2))) float f32x2;

__launch_bounds__(512, 4)
__global__ void cgblock_kernel(const float* __restrict__ x,
                               const float* __restrict__ soft_w1,  // [G, Cg]
                               const float* __restrict__ soft_w2,  // [C, G]
                               const float* __restrict__ top_w1,   // [G, K]
                               const float* __restrict__ top_w2,   // [C, G]
                               const float* __restrict__ r,        // [2]
                               float* __restrict__ out) {
    __shared__ f32x2 Ys[G_][64];
    __shared__ f32x2 Yt[G_][64];

    const int lane = threadIdx.x & 63;
    const int g = __builtin_amdgcn_readfirstlane(threadIdx.x >> 6);
    const int blk = blockIdx.x;
    const int b = blk >> 7;                          // 128 blocks per image
    const int s = ((blk & 127) << 7) | (lane << 1);  // 128 positions per block

    const long base = (long)(b * C_ + g * CG_) * HW_ + s;
    const f32x2* xp = (const f32x2*)(x + base);

    // branch mixing weights: softmax(r) -> rt (top), rs (soft)
    const float e0 = __expf(r[0]);
    const float e1 = __expf(r[1]);
    const float rt = e0 / (e0 + e1);
    const float rs = e1 / (e0 + e1);

    // ---- load 32 channels x 2 positions (512 B per wave-instruction) ----
    float va[CG_], vb[CG_];
#pragma unroll
    for (int c = 0; c < CG_; ++c) {
        const f32x2 L = __builtin_nontemporal_load(xp + c * (HW_ / 2));
        va[c] = L.x;
        vb[c] = L.y;
    }

    // ---- softmax branch (both positions) ----
    float ma = va[0], mb = vb[0];
#pragma unroll
    for (int c = 1; c < CG_; ++c) {
        ma = fmaxf(ma, va[c]);
        mb = fmaxf(mb, vb[c]);
    }
    float Za = 0.f, Zb = 0.f, aa = 0.f, ab = 0.f;
#pragma unroll
    for (int c = 0; c < CG_; ++c) {
        const float w1 = soft_w1[g * CG_ + c];       // wave-uniform -> s_load
        const float ea = __expf(va[c] - ma);
        const float eb = __expf(vb[c] - mb);
        Za += ea;
        Zb += eb;
        aa = fmaf(va[c] * ea, w1, aa);
        ab = fmaf(vb[c] * eb, w1, ab);
    }
    const float ysa = aa / Za;
    const float ysb = ab / Zb;

    // ---- top-4 branch: branchless insertion network (both positions) ----
    float a0 = -INFINITY, a1 = -INFINITY, a2 = -INFINITY, a3 = -INFINITY;
    float b0 = -INFINITY, b1 = -INFINITY, b2 = -INFINITY, b3 = -INFINITY;
#pragma unroll
    for (int c = 0; c < CG_; ++c) {
        float u = va[c];
        float d0 = fminf(a0, u); a0 = fmaxf(a0, u);
        float d1 = fminf(a1, d0); a1 = fmaxf(a1, d0);
        float d2 = fminf(a2, d1); a2 = fmaxf(a2, d1);
        a3 = fmaxf(a3, d2);
        u = vb[c];
        d0 = fminf(b0, u); b0 = fmaxf(b0, u);
        d1 = fminf(b1, d0); b1 = fmaxf(b1, d0);
        d2 = fminf(b2, d1); b2 = fmaxf(b2, d1);
        b3 = fmaxf(b3, d2);
    }
    const float tw0 = top_w1[g * K_ + 0], tw1 = top_w1[g * K_ + 1];
    const float tw2 = top_w1[g * K_ + 2], tw3 = top_w1[g * K_ + 3];
    const float yta = a0 * tw0 + a1 * tw1 + a2 * tw2 + a3 * tw3;
    const float ytb = b0 * tw0 + b1 * tw1 + b2 * tw2 + b3 * tw3;

    // ---- exchange per-position group features through LDS (pre-scaled) ----
    Ys[g][lane] = f32x2{ysa * rs, ysb * rs};
    Yt[g][lane] = f32x2{yta * rt, ytb * rt};
    __syncthreads();

    // ---- epilogue: va/vb += sum_gg (w2s*Ys + w2t*Yt), SGPR coeffs ----
    // gg-outer + accumulate-in-place keeps the live set at va/vb only
    // (no yf[8]/tf[8] register block).
    const float* w2s = soft_w2 + g * CG_ * G_;
    const float* w2t = top_w2 + g * CG_ * G_;
#pragma unroll
    for (int gg = 0; gg < G_; ++gg) {
        const f32x2 yf = Ys[gg][lane];
        const f32x2 tf = Yt[gg][lane];
#pragma unroll
        for (int c = 0; c < CG_; ++c) {
            const float cs = w2s[c * G_ + gg];       // wave-uniform -> s_load
            const float ct = w2t[c * G_ + gg];
            va[c] = fmaf(cs, yf.x, va[c]);
            vb[c] = fmaf(cs, yf.y, vb[c]);
            va[c] = fmaf(ct, tf.x, va[c]);
            vb[c] = fmaf(ct, tf.y, vb[c]);
        }
    }

    // ---- store 32 channels x 2 positions ----
    f32x2* op = (f32x2*)(out + base);
#pragma unroll
    for (int c = 0; c < CG_; ++c) {
        __builtin_nontemporal_store(f32x2{va[c], vb[c]}, op + c * (HW_ / 2));
    }
}

extern "C" void kernel_launch(void* const* d_in, const int* in_sizes, int n_in,
                              void* d_out, int out_size, void* d_ws, size_t ws_size,
                              hipStream_t stream) {
    const float* x       = (const float*)d_in[0];
    const float* soft_w1 = (const float*)d_in[1];
    const float* soft_w2 = (const float*)d_in[2];
    const float* top_w1  = (const float*)d_in[3];
    const float* top_w2  = (const float*)d_in[4];
    const float* r       = (const float*)d_in[5];
    float* out = (float*)d_out;

    // grid: B * (HW/128) = 16 * 128 = 2048 blocks; 512 threads = 8 waves
    cgblock_kernel<<<dim3(2048), dim3(512), 0, stream>>>(
        x, soft_w1, soft_w2, top_w1, top_w2, r, out);
}

// Round 3
// 435.869 us; speedup vs baseline: 1.0173x; 1.0173x over previous
//
#include <hip/hip_runtime.h>
#include <math.h>

// CGBlock fused kernel for MI355X (gfx950) — round 4.
//
// Shapes: B=16, C=256, H=W=128, G=8, Cg=32, K=4.
// out = x + rt*(top_w2 @ yt) + rs*(soft_w2 @ y)     [rt+rs=1 folds the mix]
//
// R4 changes vs R3 (theory: non-overlapped VALU is the residual ~30 us;
// shrink it):
//  - Top-4 maintained with the max+3*med3 idiom (v_med3_f32): 4 ops/elem
//    (depth 1, all operands are OLD slot values) vs 7-op min/max insertion
//    chain. Bit-identical selection.
//  - Both spatial positions processed as f32x2 vectors end-to-end with
//    __builtin_elementwise_fma/max so the compiler can emit full-rate
//    v_pk_fma_f32 (the 157 TF fp32 peak IS the packed rate): epilogue
//    1024 scalar FMA -> 512 pk FMA; softmax accumulation also packed.
//  - Ys/Yt fused into one f32x4 LDS array: 1 ds_write_b128 per thread,
//    8 ds_read_b128 after the barrier (was 16 b64). c-outer epilogue
//    stores each channel right after its 16 pk-FMAs so the store stream
//    overlaps the epilogue VALU.
//
// Mapping (unchanged): block = 512 threads = 8 waves; wave w = group w;
// lane = 2 consecutive spatial positions (f32x2, 512 B per wave-instr,
// nontemporal both ways, zero over-fetch). g is wave-uniform via
// readfirstlane so every weight index is an SGPR -> s_load operands.

#define G_ 8
#define K_ 4
#define CG_ 32
#define C_ 256
#define HW_ (128 * 128)

typedef __attribute__((ext_vector_type(2))) float f32x2;
typedef __attribute__((ext_vector_type(4))) float f32x4;

static __device__ __forceinline__ f32x2 pk2(float s) { return f32x2{s, s}; }

static __device__ __forceinline__ f32x2 maxv(f32x2 a, f32x2 b) {
    return __builtin_elementwise_max(a, b);
}

static __device__ __forceinline__ f32x2 fmav(f32x2 a, f32x2 b, f32x2 c) {
    return __builtin_elementwise_fma(a, b, c);
}

// per-component median-of-3 (v_med3_f32)
static __device__ __forceinline__ f32x2 med3v(f32x2 u, f32x2 x, f32x2 y) {
    return f32x2{__builtin_amdgcn_fmed3f(u.x, x.x, y.x),
                 __builtin_amdgcn_fmed3f(u.y, x.y, y.y)};
}

__launch_bounds__(512, 4)
__global__ void cgblock_kernel(const float* __restrict__ x,
                               const float* __restrict__ soft_w1,  // [G, Cg]
                               const float* __restrict__ soft_w2,  // [C, G]
                               const float* __restrict__ top_w1,   // [G, K]
                               const float* __restrict__ top_w2,   // [C, G]
                               const float* __restrict__ r,        // [2]
                               float* __restrict__ out) {
    // Y[g][lane] = {ys.x*rs, ys.y*rs, yt.x*rt, yt.y*rt}
    __shared__ f32x4 Y[G_][64];

    const int lane = threadIdx.x & 63;
    const int g = __builtin_amdgcn_readfirstlane(threadIdx.x >> 6);
    const int blk = blockIdx.x;
    const int b = blk >> 7;                          // 128 blocks per image
    const int s = ((blk & 127) << 7) | (lane << 1);  // 128 positions per block

    const long base = (long)(b * C_ + g * CG_) * HW_ + s;
    const f32x2* xp = (const f32x2*)(x + base);

    // branch mixing weights: softmax(r) -> rt (top), rs (soft)
    const float e0 = __expf(r[0]);
    const float e1 = __expf(r[1]);
    const float rt = e0 / (e0 + e1);
    const float rs = e1 / (e0 + e1);

    // ---- load 32 channels x 2 positions (512 B per wave-instruction) ----
    f32x2 v[CG_];
#pragma unroll
    for (int c = 0; c < CG_; ++c) {
        v[c] = __builtin_nontemporal_load(xp + c * (HW_ / 2));
    }

    // ---- softmax branch: max via depth-5 tree, packed accumulate ----
    f32x2 mm[16];
#pragma unroll
    for (int i = 0; i < 16; ++i) mm[i] = maxv(v[i], v[i + 16]);
#pragma unroll
    for (int st = 8; st >= 1; st >>= 1) {
#pragma unroll
        for (int i = 0; i < st; ++i) mm[i] = maxv(mm[i], mm[i + st]);
    }
    const f32x2 m = mm[0];

    f32x2 Z = pk2(0.f), acc = pk2(0.f);
#pragma unroll
    for (int c = 0; c < CG_; ++c) {
        const float w1 = soft_w1[g * CG_ + c];       // wave-uniform -> s_load
        const f32x2 d = v[c] - m;                    // pk_add
        const f32x2 e = f32x2{__expf(d.x), __expf(d.y)};
        Z += e;                                      // pk_add
        acc = fmav(v[c] * e, pk2(w1), acc);          // pk_mul + pk_fma
    }
    const f32x2 ys = f32x2{acc.x / Z.x, acc.y / Z.y};

    // ---- top-4 branch: max + 3x med3 per element (depth-1, ILP-friendly) --
    f32x2 A0 = pk2(-INFINITY), A1 = pk2(-INFINITY);
    f32x2 A2 = pk2(-INFINITY), A3 = pk2(-INFINITY);
#pragma unroll
    for (int c = 0; c < CG_; ++c) {
        const f32x2 u = v[c];
        const f32x2 n0 = maxv(A0, u);
        const f32x2 n1 = med3v(u, A0, A1);
        const f32x2 n2 = med3v(u, A1, A2);
        const f32x2 n3 = med3v(u, A2, A3);
        A0 = n0; A1 = n1; A2 = n2; A3 = n3;
    }
    const float tw0 = top_w1[g * K_ + 0], tw1 = top_w1[g * K_ + 1];
    const float tw2 = top_w1[g * K_ + 2], tw3 = top_w1[g * K_ + 3];
    f32x2 yt = A3 * pk2(tw3);
    yt = fmav(A2, pk2(tw2), yt);
    yt = fmav(A1, pk2(tw1), yt);
    yt = fmav(A0, pk2(tw0), yt);

    // ---- exchange per-position group features through LDS (pre-scaled) ----
    const f32x2 yss = ys * pk2(rs);
    const f32x2 ytt = yt * pk2(rt);
    Y[g][lane] = f32x4{yss.x, yss.y, ytt.x, ytt.y};
    __syncthreads();

    f32x4 yv[G_];
#pragma unroll
    for (int gg = 0; gg < G_; ++gg) yv[gg] = Y[gg][lane];  // ds_read_b128

    // ---- epilogue: out[c] = x[c] + sum_gg (w2s*ys + w2t*yt), pk FMAs ----
    // c-outer + immediate store: store stream overlaps epilogue VALU.
    f32x2* op = (f32x2*)(out + base);
    const float* w2s = soft_w2 + g * CG_ * G_;
    const float* w2t = top_w2 + g * CG_ * G_;
#pragma unroll
    for (int c = 0; c < CG_; ++c) {
        f32x2 o = v[c];
#pragma unroll
        for (int gg = 0; gg < G_; ++gg) {
            const float cs = w2s[c * G_ + gg];       // wave-uniform -> s_load
            const float ct = w2t[c * G_ + gg];
            const f32x2 yf = f32x2{yv[gg].x, yv[gg].y};
            const f32x2 tf = f32x2{yv[gg].z, yv[gg].w};
            o = fmav(pk2(cs), yf, o);                // v_pk_fma_f32
            o = fmav(pk2(ct), tf, o);                // v_pk_fma_f32
        }
        __builtin_nontemporal_store(o, op + c * (HW_ / 2));
    }
}

extern "C" void kernel_launch(void* const* d_in, const int* in_sizes, int n_in,
                              void* d_out, int out_size, void* d_ws, size_t ws_size,
                              hipStream_t stream) {
    const float* x       = (const float*)d_in[0];
    const float* soft_w1 = (const float*)d_in[1];
    const float* soft_w2 = (const float*)d_in[2];
    const float* top_w1  = (const float*)d_in[3];
    const float* top_w2  = (const float*)d_in[4];
    const float* r       = (const float*)d_in[5];
    float* out = (float*)d_out;

    // grid: B * (HW/128) = 16 * 128 = 2048 blocks; 512 threads = 8 waves
    cgblock_kernel<<<dim3(2048), dim3(512), 0, stream>>>(
        x, soft_w1, soft_w2, top_w1, top_w2, r, out);
}